// Round 14
// baseline (188.760 us; speedup 1.0000x reference)
//
#include <hip/hip_runtime.h>

#define B_TOT 16384
#define DIMN  4096
#define EPSF  1e-10f

typedef __attribute__((ext_vector_type(8))) short bf16x8;
typedef __attribute__((ext_vector_type(4))) float f32x4;
typedef unsigned short u16;

__device__ __forceinline__ u16 f2bf(float f) {
  unsigned int u = __float_as_uint(f);
  u += 0x7FFFu + ((u >> 16) & 1u);        // round-to-nearest-even
  return (u16)(u >> 16);
}
__device__ __forceinline__ unsigned int pk2(float a, float b) {
  return (unsigned int)f2bf(a) | ((unsigned int)f2bf(b) << 16);
}

__device__ __forceinline__ void normalize8(float* rr, float* ii) {
  float n2 = 0.f;
#pragma unroll
  for (int q = 0; q < 8; q++) n2 += rr[q] * rr[q] + ii[q] * ii[q];
  float n = sqrtf(n2);
  if (n < EPSF) {
#pragma unroll
    for (int q = 0; q < 8; q++) { rr[q] = 0.f; ii[q] = 0.f; }
    rr[0] = 1.f;
  } else {
    float inv = 1.f / n;
#pragma unroll
    for (int q = 0; q < 8; q++) { rr[q] *= inv; ii[q] *= inv; }
  }
}

// K0: convert W_enc f32 -> bf16 into ws (64 blocks x 256 thr x 4 elems)
__global__ __launch_bounds__(256) void k_prep(const float* __restrict__ wenc,
                                              u16* __restrict__ wbf) {
  int i = (blockIdx.x * 256 + threadIdx.x) * 4;
  float4 v = *reinterpret_cast<const float4*>(wenc + i);
  ushort4 o;
  o.x = f2bf(v.x); o.y = f2bf(v.y); o.z = f2bf(v.z); o.w = f2bf(v.w);
  *reinterpret_cast<ushort4*>(wbf + i) = o;
}

// K1: MFMA enc GEMM + evolve + metrics + decode.
// 256 blocks x 512 thr (8 waves). Block = 64 rows. Wave wid: g=wid&3 owns rows
// r0+g*16..+15, h=wid>>2 owns K-half [h*2048,(h+1)*2048). Per step: A = x 16x32
// (f32 global -> bf16 regs), B = wbf 32x16 (bf16 from L2), one 16x16x32 MFMA.
// A lane l: row=l&15, k=(l>>4)*8+j. B lane l: col(feat)=l&15, k=(l>>4)*8+j.
// C lane l: col=l&15, row=(l>>4)*4+reg   [m89-verified layout]
__global__ __launch_bounds__(512) void k_encdec(
    const float* __restrict__ x, const u16* __restrict__ wbf,
    const float* __restrict__ benc, const float* __restrict__ phase,
    const float* __restrict__ disorder, const float* __restrict__ wdec,
    const float* __restrict__ bdec, float* __restrict__ out,
    float* __restrict__ blocksum) {
  __shared__ float lds[2176 + 1088 + 512];     // encP[2][64][17] | encL[64][17] | absL[64][8]
  float* const encP = lds;
  float* const encL = lds + 2176;
  float* const absL = lds + 2176 + 1088;

  const int t = threadIdx.x;
  const int l = t & 63;
  const int wid = t >> 6;
  const int r0 = blockIdx.x * 64;
  const int g = wid & 3, h = wid >> 2;
  const int rloc = l & 15;
  const int koff = (l >> 4) * 8;

  const float* __restrict__ xp = x + (size_t)(r0 + g * 16 + rloc) * DIMN + h * 2048 + koff;
  const u16* __restrict__ wp = wbf + (size_t)rloc * DIMN + h * 2048 + koff;

  f32x4 acc = {0.f, 0.f, 0.f, 0.f};
  float4 a0 = *reinterpret_cast<const float4*>(xp);
  float4 a1 = *reinterpret_cast<const float4*>(xp + 4);
  uint4 bq = *reinterpret_cast<const uint4*>(wp);

  for (int s = 0; s < 64; ++s) {               // K-half = 64 steps of 32
    float4 c0 = a0, c1 = a1;
    uint4 cb = bq;
    if (s < 63) {                              // prefetch next step
      a0 = *reinterpret_cast<const float4*>(xp + (s + 1) * 32);
      a1 = *reinterpret_cast<const float4*>(xp + (s + 1) * 32 + 4);
      bq = *reinterpret_cast<const uint4*>(wp + (s + 1) * 32);
    }
    union { unsigned int u[4]; bf16x8 v; } A, B;
    A.u[0] = pk2(c0.x, c0.y); A.u[1] = pk2(c0.z, c0.w);
    A.u[2] = pk2(c1.x, c1.y); A.u[3] = pk2(c1.z, c1.w);
    B.u[0] = cb.x; B.u[1] = cb.y; B.u[2] = cb.z; B.u[3] = cb.w;
    acc = __builtin_amdgcn_mfma_f32_16x16x32_bf16(A.v, B.v, acc, 0, 0, 0);
  }

  // scatter C tile to LDS: encP[h][g*16 + (l>>4)*4 + j][feat = l&15]
#pragma unroll
  for (int j = 0; j < 4; ++j) {
    const int row64 = g * 16 + (l >> 4) * 4 + j;
    encP[h * 1088 + row64 * 17 + rloc] = acc[j];
  }
  __syncthreads();

  // reduce K-halves -> encL[row*17 + feat]
  if (t < 256) {
#pragma unroll
    for (int p = 0; p < 4; ++p) {
      const int idx = t * 4 + p;               // 0..1023
      const int row = idx >> 4, ft = idx & 15;
      encL[row * 17 + ft] = encP[row * 17 + ft] + encP[1088 + row * 17 + ft];
    }
  }
  __syncthreads();

  if (t < 64) {                                // wave 0: one thread per row
    const int r = r0 + t;
    float e[16];
#pragma unroll
    for (int k = 0; k < 16; k++) e[k] = tanhf(encL[t * 17 + k] + benc[k]);

    float re[8], im[8];
#pragma unroll
    for (int q = 0; q < 8; q++) {
      float ph = 0.1f * phase[q];
      float cc = cosf(ph), ss = sinf(ph);
      re[q] = e[q] * cc - e[8 + q] * ss + 0.017677669529663688f;  // +0.05/sqrt(8)
      im[q] = e[q] * ss + e[8 + q] * cc;
    }
    normalize8(re, im);

    float dd0 = disorder[0], dd1 = disorder[1], dd2 = disorder[2];
    float hz[8];
#pragma unroll
    for (int i = 0; i < 8; i++)
      hz[i] = ((i & 4) ? -dd0 : dd0) + ((i & 2) ? -dd1 : dd1) + ((i & 1) ? -dd2 : dd2);

#pragma unroll
    for (int step = 0; step < 2; step++) {
      float tt = 0.02f * (float)r + 0.01f * (float)step;
      float drive = 0.5f + 0.2f * sinf(1.61803398874989485f * tt);
      float nr[8], ni[8];
#pragma unroll
      for (int j = 0; j < 8; j++) {
        float hr = drive * (re[j ^ 1] + re[j ^ 2] + re[j ^ 4]) + hz[j] * re[j];
        float hi = drive * (im[j ^ 1] + im[j ^ 2] + im[j ^ 4]) + hz[j] * im[j];
        nr[j] = re[j] + 1e-4f * hi;            // amps - 1j*1e-4*Ha
        ni[j] = im[j] - 1e-4f * hr;
      }
      normalize8(nr, ni);
#pragma unroll
      for (int j = 0; j < 8; j++) { re[j] = nr[j]; im[j] = ni[j]; }
    }

    float tr = 0.f, s2 = 0.f;
#pragma unroll
    for (int q = 0; q < 8; q++) {
      float a2 = re[q] * re[q] + im[q] * im[q];
      tr += a2; s2 += a2 * a2;
      absL[t * 8 + q] = sqrtf(a2);
    }
    float trp = tr + EPSF;
    float purity = tr * tr / (trp * trp);
    float coh = sqrtf(fmaxf(tr * tr - s2, 0.f)) / trp;
    float lam = fminf(fmaxf(tr / trp, EPSF), 1.f);   // rho rank-1
    float denom = lam + 8.f * EPSF;
    float e1 = lam / denom, er = EPSF / denom;
    float ent = -(e1 * log2f(e1 + EPSF) + 7.f * er * log2f(er + EPSF));

    float sp = purity, sc2 = coh, sh = ent;
#pragma unroll
    for (int off = 32; off > 0; off >>= 1) {
      sp += __shfl_xor(sp, off);
      sc2 += __shfl_xor(sc2, off);
      sh += __shfl_xor(sh, off);
    }
    if (t == 0) {
      blocksum[blockIdx.x * 3 + 0] = sp;
      blocksum[blockIdx.x * 3 + 1] = sc2;
      blocksum[blockIdx.x * 3 + 2] = sh;
    }
  }
  __syncthreads();                             // absL ready

  // decode: 64 rows x 4096 cols; wdec reg-cached (L2), coalesced f4 stores
#pragma unroll
  for (int g2 = 0; g2 < 2; ++g2) {
    const int c4 = g2 * 2048 + t * 4;
    float wd[4][8];
#pragma unroll
    for (int j = 0; j < 4; ++j) {
      float4 a = *reinterpret_cast<const float4*>(wdec + (size_t)(c4 + j) * 8);
      float4 b = *reinterpret_cast<const float4*>(wdec + (size_t)(c4 + j) * 8 + 4);
      wd[j][0] = a.x; wd[j][1] = a.y; wd[j][2] = a.z; wd[j][3] = a.w;
      wd[j][4] = b.x; wd[j][5] = b.y; wd[j][6] = b.z; wd[j][7] = b.w;
    }
    float4 bd = *reinterpret_cast<const float4*>(bdec + c4);
    for (int r = 0; r < 64; ++r) {
      float4 a0v = *reinterpret_cast<const float4*>(&absL[r * 8]);     // broadcast
      float4 a1v = *reinterpret_cast<const float4*>(&absL[r * 8 + 4]);
      float aq[8] = {a0v.x, a0v.y, a0v.z, a0v.w, a1v.x, a1v.y, a1v.z, a1v.w};
      float o0 = bd.x, o1 = bd.y, o2 = bd.z, o3 = bd.w;
#pragma unroll
      for (int q = 0; q < 8; ++q) {
        o0 = fmaf(aq[q], wd[0][q], o0);
        o1 = fmaf(aq[q], wd[1][q], o1);
        o2 = fmaf(aq[q], wd[2][q], o2);
        o3 = fmaf(aq[q], wd[3][q], o3);
      }
      *reinterpret_cast<float4*>(out + (size_t)(r0 + r) * DIMN + c4) =
          make_float4(o0, o1, o2, o3);
    }
  }
}

// K2: finalize metric means (256 block partials)
__global__ void k_final(const float* __restrict__ blocksum,
                        float* __restrict__ out) {
  const int t = threadIdx.x;
  float s0 = 0.f, s1 = 0.f, s2 = 0.f;
  for (int b = t; b < 256; b += 64) {
    s0 += blocksum[b * 3 + 0];
    s1 += blocksum[b * 3 + 1];
    s2 += blocksum[b * 3 + 2];
  }
#pragma unroll
  for (int off = 32; off > 0; off >>= 1) {
    s0 += __shfl_down(s0, off);
    s1 += __shfl_down(s1, off);
    s2 += __shfl_down(s2, off);
  }
  if (t == 0) {
    out[(size_t)B_TOT * DIMN + 0] = s0 / 16384.f;
    out[(size_t)B_TOT * DIMN + 1] = s1 / 16384.f;
    out[(size_t)B_TOT * DIMN + 2] = s2 / 16384.f;
  }
}

extern "C" void kernel_launch(void* const* d_in, const int* in_sizes, int n_in,
                              void* d_out, int out_size, void* d_ws, size_t ws_size,
                              hipStream_t stream) {
  const float *x = nullptr, *wenc = nullptr, *benc = nullptr, *phase = nullptr,
              *wdec = nullptr, *bdec = nullptr, *dis = nullptr;
  for (int i = 0; i < n_in; i++) {
    switch (in_sizes[i]) {
      case 67108864: x = (const float*)d_in[i]; break;      // 16384*4096
      case 65536:    wenc = (const float*)d_in[i]; break;   // 16*4096
      case 16:       benc = (const float*)d_in[i]; break;
      case 8:        phase = (const float*)d_in[i]; break;
      case 32768:    wdec = (const float*)d_in[i]; break;   // 4096*8
      case 4096:     bdec = (const float*)d_in[i]; break;
      case 3:        dis = (const float*)d_in[i]; break;
      default: break;
    }
  }

  u16* wbf = (u16*)d_ws;                        // 65536 bf16 = 128 KB
  float* bsum = (float*)d_ws + 32768;           // after wbf
  float* out = (float*)d_out;

  hipLaunchKernelGGL(k_prep, dim3(64), dim3(256), 0, stream, wenc, wbf);
  hipLaunchKernelGGL(k_encdec, dim3(256), dim3(512), 0, stream,
                     x, wbf, benc, phase, dis, wdec, bdec, out, bsum);
  hipLaunchKernelGGL(k_final, dim3(1), dim3(64), 0, stream, bsum, out);
}

// Round 15
// 149.000 us; speedup vs baseline: 1.2668x; 1.2668x over previous
//
#include <hip/hip_runtime.h>

#define B_TOT 16384
#define DIMN  4096
#define EPSF  1e-10f

typedef __attribute__((ext_vector_type(8))) short bf16x8;
typedef __attribute__((ext_vector_type(4))) float f32x4;
typedef unsigned short u16;

__device__ __forceinline__ u16 f2bf(float f) {
  unsigned int u = __float_as_uint(f);
  u += 0x7FFFu + ((u >> 16) & 1u);        // round-to-nearest-even
  return (u16)(u >> 16);
}
__device__ __forceinline__ unsigned int pk2(float a, float b) {
  return (unsigned int)f2bf(a) | ((unsigned int)f2bf(b) << 16);
}

__device__ __forceinline__ void normalize8(float* rr, float* ii) {
  float n2 = 0.f;
#pragma unroll
  for (int q = 0; q < 8; q++) n2 += rr[q] * rr[q] + ii[q] * ii[q];
  float n = sqrtf(n2);
  if (n < EPSF) {
#pragma unroll
    for (int q = 0; q < 8; q++) { rr[q] = 0.f; ii[q] = 0.f; }
    rr[0] = 1.f;
  } else {
    float inv = 1.f / n;
#pragma unroll
    for (int q = 0; q < 8; q++) { rr[q] *= inv; ii[q] *= inv; }
  }
}

// K0: convert W_enc f32 -> bf16 into ws
__global__ __launch_bounds__(256) void k_prep(const float* __restrict__ wenc,
                                              u16* __restrict__ wbf) {
  int i = (blockIdx.x * 256 + threadIdx.x) * 4;
  float4 v = *reinterpret_cast<const float4*>(wenc + i);
  ushort4 o;
  o.x = f2bf(v.x); o.y = f2bf(v.y); o.z = f2bf(v.z); o.w = f2bf(v.w);
  *reinterpret_cast<ushort4*>(wbf + i) = o;
}

#define LDX(p)  (*reinterpret_cast<const float4*>(p))
#define LDW(p)  (*reinterpret_cast<const uint4*>(p))
#define MF(A0v, A1v, Bv)                                                    \
  do {                                                                      \
    union { unsigned int u[4]; bf16x8 v; } A_, B_;                          \
    A_.u[0] = pk2((A0v).x, (A0v).y); A_.u[1] = pk2((A0v).z, (A0v).w);       \
    A_.u[2] = pk2((A1v).x, (A1v).y); A_.u[3] = pk2((A1v).z, (A1v).w);       \
    B_.u[0] = (Bv).x; B_.u[1] = (Bv).y; B_.u[2] = (Bv).z; B_.u[3] = (Bv).w; \
    acc = __builtin_amdgcn_mfma_f32_16x16x32_bf16(A_.v, B_.v, acc, 0, 0, 0);\
  } while (0)

// K1: MFMA enc GEMM (4-deep prefetch) + evolve + metrics + decode.
// 1024 blocks x 256 thr (4 waves) -> 4 blocks/CU, phases overlap across blocks.
// Block = 16 rows. Wave h owns K-quarter [h*1024,(h+1)*1024): 32 steps of K=32.
// A lane l: row=l&15, k=(l>>4)*8+j (f32 global -> bf16 reg). B same from wbf (L2).
// C lane l: col(feat)=l&15, row=(l>>4)*4+reg  [m89-verified; R14-validated]
__global__ __launch_bounds__(256) void k_encdec(
    const float* __restrict__ x, const u16* __restrict__ wbf,
    const float* __restrict__ benc, const float* __restrict__ phase,
    const float* __restrict__ disorder, const float* __restrict__ wdec,
    const float* __restrict__ bdec, float* __restrict__ out,
    float* __restrict__ blocksum) {
  __shared__ float encP[4 * 16 * 17];          // per-K-quarter partials
  __shared__ float encL[16 * 17];
  __shared__ float absL[16 * 8];

  const int t = threadIdx.x;
  const int l = t & 63;
  const int h = t >> 6;                        // wave = K-quarter 0..3
  const int r0 = blockIdx.x * 16;
  const int rloc = l & 15;
  const int koff = (l >> 4) * 8;

  const float* __restrict__ xp = x + (size_t)(r0 + rloc) * DIMN + h * 1024 + koff;
  const u16* __restrict__ wp = wbf + (size_t)rloc * DIMN + h * 1024 + koff;

  f32x4 acc = {0.f, 0.f, 0.f, 0.f};
  // 4-deep pipeline registers (static names, no runtime indexing)
  float4 a00 = LDX(xp +  0), a01 = LDX(xp +  4);
  float4 a10 = LDX(xp + 32), a11 = LDX(xp + 36);
  float4 a20 = LDX(xp + 64), a21 = LDX(xp + 68);
  float4 a30 = LDX(xp + 96), a31 = LDX(xp + 100);
  uint4 b0 = LDW(wp + 0), b1 = LDW(wp + 32), b2 = LDW(wp + 64), b3 = LDW(wp + 96);

  for (int g = 0; g < 7; ++g) {                // 7 groups with prefetch
    const int nb = (g * 4 + 4) * 32;
    MF(a00, a01, b0);
    a00 = LDX(xp + nb);      a01 = LDX(xp + nb + 4);      b0 = LDW(wp + nb);
    MF(a10, a11, b1);
    a10 = LDX(xp + nb + 32); a11 = LDX(xp + nb + 36);     b1 = LDW(wp + nb + 32);
    MF(a20, a21, b2);
    a20 = LDX(xp + nb + 64); a21 = LDX(xp + nb + 68);     b2 = LDW(wp + nb + 64);
    MF(a30, a31, b3);
    a30 = LDX(xp + nb + 96); a31 = LDX(xp + nb + 100);    b3 = LDW(wp + nb + 96);
  }
  MF(a00, a01, b0); MF(a10, a11, b1); MF(a20, a21, b2); MF(a30, a31, b3);

  // scatter C to LDS: encP[h][(l>>4)*4+j][feat=l&15]
#pragma unroll
  for (int j = 0; j < 4; ++j)
    encP[h * 272 + ((l >> 4) * 4 + j) * 17 + rloc] = acc[j];
  __syncthreads();

  // reduce 4 K-quarters -> encL[row*17+feat]
  if (t < 64) {
#pragma unroll
    for (int p = 0; p < 4; ++p) {
      const int idx = t * 4 + p;               // 0..255
      const int row = idx >> 4, ft = idx & 15;
      encL[row * 17 + ft] = (encP[row * 17 + ft] + encP[272 + row * 17 + ft]) +
                            (encP[544 + row * 17 + ft] + encP[816 + row * 17 + ft]);
    }
  }
  __syncthreads();

  if (t < 16) {                                // one thread per row: evolve+metrics
    const int r = r0 + t;
    float e[16];
#pragma unroll
    for (int k = 0; k < 16; k++) e[k] = tanhf(encL[t * 17 + k] + benc[k]);

    float re[8], im[8];
#pragma unroll
    for (int q = 0; q < 8; q++) {
      float ph = 0.1f * phase[q];
      float cc = cosf(ph), ss = sinf(ph);
      re[q] = e[q] * cc - e[8 + q] * ss + 0.017677669529663688f;  // +0.05/sqrt(8)
      im[q] = e[q] * ss + e[8 + q] * cc;
    }
    normalize8(re, im);

    float dd0 = disorder[0], dd1 = disorder[1], dd2 = disorder[2];
    float hz[8];
#pragma unroll
    for (int i = 0; i < 8; i++)
      hz[i] = ((i & 4) ? -dd0 : dd0) + ((i & 2) ? -dd1 : dd1) + ((i & 1) ? -dd2 : dd2);

#pragma unroll
    for (int step = 0; step < 2; step++) {
      float tt = 0.02f * (float)r + 0.01f * (float)step;
      float drive = 0.5f + 0.2f * sinf(1.61803398874989485f * tt);
      float nr[8], ni[8];
#pragma unroll
      for (int j = 0; j < 8; j++) {
        float hr = drive * (re[j ^ 1] + re[j ^ 2] + re[j ^ 4]) + hz[j] * re[j];
        float hi = drive * (im[j ^ 1] + im[j ^ 2] + im[j ^ 4]) + hz[j] * im[j];
        nr[j] = re[j] + 1e-4f * hi;            // amps - 1j*1e-4*Ha
        ni[j] = im[j] - 1e-4f * hr;
      }
      normalize8(nr, ni);
#pragma unroll
      for (int j = 0; j < 8; j++) { re[j] = nr[j]; im[j] = ni[j]; }
    }

    float tr = 0.f, s2 = 0.f;
#pragma unroll
    for (int q = 0; q < 8; q++) {
      float a2 = re[q] * re[q] + im[q] * im[q];
      tr += a2; s2 += a2 * a2;
      absL[t * 8 + q] = sqrtf(a2);
    }
    float trp = tr + EPSF;
    float purity = tr * tr / (trp * trp);
    float coh = sqrtf(fmaxf(tr * tr - s2, 0.f)) / trp;
    float lam = fminf(fmaxf(tr / trp, EPSF), 1.f);   // rho rank-1
    float denom = lam + 8.f * EPSF;
    float e1 = lam / denom, er = EPSF / denom;
    float ent = -(e1 * log2f(e1 + EPSF) + 7.f * er * log2f(er + EPSF));

    float sp = purity, sc2 = coh, sh = ent;
#pragma unroll
    for (int off = 8; off > 0; off >>= 1) {    // 16 active lanes
      sp += __shfl_xor(sp, off);
      sc2 += __shfl_xor(sc2, off);
      sh += __shfl_xor(sh, off);
    }
    if (t == 0) {
      blocksum[blockIdx.x * 3 + 0] = sp;
      blocksum[blockIdx.x * 3 + 1] = sc2;
      blocksum[blockIdx.x * 3 + 2] = sh;
    }
  }
  __syncthreads();                             // absL ready

  // decode: 16 rows x 4096 cols; 4 col-passes; wdec reg-cached (L2)
#pragma unroll
  for (int g2 = 0; g2 < 4; ++g2) {
    const int c4 = g2 * 1024 + t * 4;
    float wd[4][8];
#pragma unroll
    for (int j = 0; j < 4; ++j) {
      float4 a = *reinterpret_cast<const float4*>(wdec + (size_t)(c4 + j) * 8);
      float4 b = *reinterpret_cast<const float4*>(wdec + (size_t)(c4 + j) * 8 + 4);
      wd[j][0] = a.x; wd[j][1] = a.y; wd[j][2] = a.z; wd[j][3] = a.w;
      wd[j][4] = b.x; wd[j][5] = b.y; wd[j][6] = b.z; wd[j][7] = b.w;
    }
    float4 bd = *reinterpret_cast<const float4*>(bdec + c4);
#pragma unroll
    for (int r = 0; r < 16; ++r) {
      float4 a0v = *reinterpret_cast<const float4*>(&absL[r * 8]);     // broadcast
      float4 a1v = *reinterpret_cast<const float4*>(&absL[r * 8 + 4]);
      float aq[8] = {a0v.x, a0v.y, a0v.z, a0v.w, a1v.x, a1v.y, a1v.z, a1v.w};
      float o0 = bd.x, o1 = bd.y, o2 = bd.z, o3 = bd.w;
#pragma unroll
      for (int q = 0; q < 8; ++q) {
        o0 = fmaf(aq[q], wd[0][q], o0);
        o1 = fmaf(aq[q], wd[1][q], o1);
        o2 = fmaf(aq[q], wd[2][q], o2);
        o3 = fmaf(aq[q], wd[3][q], o3);
      }
      *reinterpret_cast<float4*>(out + (size_t)(r0 + r) * DIMN + c4) =
          make_float4(o0, o1, o2, o3);
    }
  }
}

// K2: finalize metric means (1024 block partials)
__global__ void k_final(const float* __restrict__ blocksum,
                        float* __restrict__ out) {
  const int t = threadIdx.x;
  float s0 = 0.f, s1 = 0.f, s2 = 0.f;
  for (int b = t; b < 1024; b += 64) {
    s0 += blocksum[b * 3 + 0];
    s1 += blocksum[b * 3 + 1];
    s2 += blocksum[b * 3 + 2];
  }
#pragma unroll
  for (int off = 32; off > 0; off >>= 1) {
    s0 += __shfl_down(s0, off);
    s1 += __shfl_down(s1, off);
    s2 += __shfl_down(s2, off);
  }
  if (t == 0) {
    out[(size_t)B_TOT * DIMN + 0] = s0 / 16384.f;
    out[(size_t)B_TOT * DIMN + 1] = s1 / 16384.f;
    out[(size_t)B_TOT * DIMN + 2] = s2 / 16384.f;
  }
}

extern "C" void kernel_launch(void* const* d_in, const int* in_sizes, int n_in,
                              void* d_out, int out_size, void* d_ws, size_t ws_size,
                              hipStream_t stream) {
  const float *x = nullptr, *wenc = nullptr, *benc = nullptr, *phase = nullptr,
              *wdec = nullptr, *bdec = nullptr, *dis = nullptr;
  for (int i = 0; i < n_in; i++) {
    switch (in_sizes[i]) {
      case 67108864: x = (const float*)d_in[i]; break;      // 16384*4096
      case 65536:    wenc = (const float*)d_in[i]; break;   // 16*4096
      case 16:       benc = (const float*)d_in[i]; break;
      case 8:        phase = (const float*)d_in[i]; break;
      case 32768:    wdec = (const float*)d_in[i]; break;   // 4096*8
      case 4096:     bdec = (const float*)d_in[i]; break;
      case 3:        dis = (const float*)d_in[i]; break;
      default: break;
    }
  }

  u16* wbf = (u16*)d_ws;                        // 65536 bf16 = 128 KB
  float* bsum = (float*)d_ws + 32768;           // after wbf
  float* out = (float*)d_out;

  hipLaunchKernelGGL(k_prep, dim3(64), dim3(256), 0, stream, wenc, wbf);
  hipLaunchKernelGGL(k_encdec, dim3(1024), dim3(256), 0, stream,
                     x, wbf, benc, phase, dis, wdec, bdec, out, bsum);
  hipLaunchKernelGGL(k_final, dim3(1), dim3(64), 0, stream, bsum, out);
}